// Round 2
// baseline (338.451 us; speedup 1.0000x reference)
//
#include <hip/hip_runtime.h>
#include <stdint.h>

#define B_  16
#define L_  1024
#define D_  768
#define K1_ 1536

typedef unsigned short u16;
typedef __attribute__((ext_vector_type(4))) float f32x4;
typedef __attribute__((ext_vector_type(8))) _Float16 f16x8;

__device__ __forceinline__ u16 f2h(float x){
    return __builtin_bit_cast(u16, (_Float16)x);
}
__device__ __forceinline__ void split_h(float x, u16 &hi, u16 &lo){
    _Float16 hh = (_Float16)x;
    hi = __builtin_bit_cast(u16, hh);
    lo = __builtin_bit_cast(u16, (_Float16)(x - (float)hh));
}

__device__ __forceinline__ void gload_lds16(const void* g, void* l){
    __builtin_amdgcn_global_load_lds((const __attribute__((address_space(1))) void*)g,
                                     (__attribute__((address_space(3))) void*)l, 16, 0, 0);
}

// ---------------- prep: split fp16 hi/lo planes for all GEMM1 operands ----------------
// Bcat[t][0:768] = w1_w[t]+q[t]; Bcat[t][768:1536] = q[t]; hA = h; w2B = w2_w
__global__ __launch_bounds__(256) void prep_a(const float* __restrict__ h, const float* __restrict__ q,
    const float* __restrict__ w1w, const float* __restrict__ w2w,
    u16* __restrict__ hAh, u16* __restrict__ hAl,
    u16* __restrict__ w2h, u16* __restrict__ w2l,
    u16* __restrict__ Bch, u16* __restrict__ Bcl, int b0, int nb)
{
    int idx = blockIdx.x * 256 + threadIdx.x;       // (bb, t, d4)
    int d4 = idx % 192;
    int t  = (idx / 192) & (L_ - 1);
    int bb = idx / (192 * L_);
    if (bb >= nb) return;
    int bg = b0 + bb;
    int d = d4 * 4;

    float4 qv  = *(const float4*)(q   + ((size_t)bg * L_ + t) * D_ + d);
    float4 w1v = *(const float4*)(w1w + (size_t)t * D_ + d);
    float4 hv  = *(const float4*)(h   + ((size_t)bg * L_ + t) * D_ + d);

    size_t bro = ((size_t)bb * L_ + t) * K1_;
    ushort4 sh, sl;
    split_h(w1v.x + qv.x, sh.x, sl.x); split_h(w1v.y + qv.y, sh.y, sl.y);
    split_h(w1v.z + qv.z, sh.z, sl.z); split_h(w1v.w + qv.w, sh.w, sl.w);
    *(ushort4*)(Bch + bro + d) = sh;
    *(ushort4*)(Bcl + bro + d) = sl;
    split_h(qv.x, sh.x, sl.x); split_h(qv.y, sh.y, sl.y);
    split_h(qv.z, sh.z, sl.z); split_h(qv.w, sh.w, sl.w);
    *(ushort4*)(Bch + bro + D_ + d) = sh;
    *(ushort4*)(Bcl + bro + D_ + d) = sl;
    size_t ho = ((size_t)bb * L_ + t) * D_ + d;
    split_h(hv.x, sh.x, sl.x); split_h(hv.y, sh.y, sl.y);
    split_h(hv.z, sh.z, sl.z); split_h(hv.w, sh.w, sl.w);
    *(ushort4*)(hAh + ho) = sh;
    *(ushort4*)(hAl + ho) = sl;
    if (bb == 0){
        float4 w2v = *(const float4*)(w2w + (size_t)t * D_ + d);
        split_h(w2v.x, sh.x, sl.x); split_h(w2v.y, sh.y, sl.y);
        split_h(w2v.z, sh.z, sl.z); split_h(w2v.w, sh.w, sl.w);
        *(ushort4*)(w2h + (size_t)t * D_ + d) = sh;
        *(ushort4*)(w2l + (size_t)t * D_ + d) = sl;
    }
}

// ---------------- transpose: qT[b][d][t] = fp16(q[b][t][d]) ----------------
__global__ __launch_bounds__(256) void prep_t(const float* __restrict__ q, u16* __restrict__ qT, int b0)
{
    __shared__ float tile[32][33];
    int bb = blockIdx.z;
    int bg = b0 + bb;
    int t0 = blockIdx.x * 32;
    int d0 = blockIdx.y * 32;
    int tx = threadIdx.x, ty = threadIdx.y;          // 32 x 8
    const float* qb = q + (size_t)bg * L_ * D_;
    #pragma unroll
    for (int i = 0; i < 4; i++){
        int t = t0 + ty + i * 8;
        tile[ty + i * 8][tx] = qb[(size_t)t * D_ + d0 + tx];
    }
    __syncthreads();
    u16* qTb = qT + (size_t)bb * D_ * L_;
    #pragma unroll
    for (int i = 0; i < 4; i++){
        int d = d0 + ty + i * 8;
        qTb[(size_t)d * L_ + t0 + tx] = f2h(tile[tx][ty + i * 8]);
    }
}

// ---------------- GEMM1: a = Acat @ Bcat^T + biases,  fp16x2 split, 3 MFMA products ----------------
__global__ __launch_bounds__(256) void gemm1(
    const u16* __restrict__ hAh, const u16* __restrict__ hAl,
    const u16* __restrict__ w2h, const u16* __restrict__ w2l,
    const u16* __restrict__ Bch, const u16* __restrict__ Bcl,
    const float* __restrict__ w1b, const float* __restrict__ w2b,
    float* __restrict__ aB)
{
    __shared__ u16 ldsAh[128 * 64];
    __shared__ u16 ldsAl[128 * 64];
    __shared__ u16 ldsBh[128 * 64];
    __shared__ u16 ldsBl[128 * 64];
    int bb = blockIdx.y;
    int sm = blockIdx.x >> 3;
    int tn = blockIdx.x & 7;
    int s0 = sm * 128, t0 = tn * 128;
    int tid = threadIdx.x;
    int lane = tid & 63, wid = tid >> 6;
    int wm = wid >> 1, wn = wid & 1;
    int l15 = lane & 15, l4 = lane >> 4;

    const u16* Ahb = hAh + (size_t)bb * L_ * D_;
    const u16* Alb = hAl + (size_t)bb * L_ * D_;
    const u16* Bhb = Bch + (size_t)bb * L_ * K1_;
    const u16* Blb = Bcl + (size_t)bb * L_ * K1_;

    f32x4 acc[4][4];
    #pragma unroll
    for (int m = 0; m < 4; m++)
        #pragma unroll
        for (int n = 0; n < 4; n++)
            acc[m][n] = (f32x4){0.f, 0.f, 0.f, 0.f};

    for (int kb = 0; kb < K1_; kb += 64){
        bool inH = (kb < D_);
        #pragma unroll
        for (int j = 0; j < 4; j++){                 // stage A hi+lo (128 rows x 64 k)
            int n = j * 256 + tid;
            int row = n >> 3, c = n & 7;
            int cc = c ^ (row & 7);                  // pre-swizzled global chunk
            int k = kb + cc * 8;
            const u16* gh = inH ? (Ahb + (size_t)(s0 + row) * D_ + k)
                                : (w2h + (size_t)(s0 + row) * D_ + (k - D_));
            const u16* gl = inH ? (Alb + (size_t)(s0 + row) * D_ + k)
                                : (w2l + (size_t)(s0 + row) * D_ + (k - D_));
            gload_lds16(gh, &ldsAh[(j * 256 + wid * 64) * 8]);
            gload_lds16(gl, &ldsAl[(j * 256 + wid * 64) * 8]);
        }
        #pragma unroll
        for (int j = 0; j < 4; j++){                 // stage B hi+lo
            int n = j * 256 + tid;
            int row = n >> 3, c = n & 7;
            int cc = c ^ (row & 7);
            size_t go = (size_t)(t0 + row) * K1_ + kb + cc * 8;
            gload_lds16(Bhb + go, &ldsBh[(j * 256 + wid * 64) * 8]);
            gload_lds16(Blb + go, &ldsBl[(j * 256 + wid * 64) * 8]);
        }
        __syncthreads();
        #pragma unroll
        for (int kk = 0; kk < 2; kk++){
            f16x8 ah[4], al[4], bh[4], bl[4];
            #pragma unroll
            for (int m = 0; m < 4; m++){
                int row = wm * 64 + m * 16 + l15;
                int c = kk * 4 + l4;
                int off = (row * 8 + (c ^ (row & 7))) * 8;
                ah[m] = *(const f16x8*)&ldsAh[off];
                al[m] = *(const f16x8*)&ldsAl[off];
            }
            #pragma unroll
            for (int n = 0; n < 4; n++){
                int row = wn * 64 + n * 16 + l15;
                int c = kk * 4 + l4;
                int off = (row * 8 + (c ^ (row & 7))) * 8;
                bh[n] = *(const f16x8*)&ldsBh[off];
                bl[n] = *(const f16x8*)&ldsBl[off];
            }
            #pragma unroll
            for (int m = 0; m < 4; m++)
                #pragma unroll
                for (int n = 0; n < 4; n++){
                    acc[m][n] = __builtin_amdgcn_mfma_f32_16x16x32_f16(ah[m], bh[n], acc[m][n], 0, 0, 0);
                    acc[m][n] = __builtin_amdgcn_mfma_f32_16x16x32_f16(ah[m], bl[n], acc[m][n], 0, 0, 0);
                    acc[m][n] = __builtin_amdgcn_mfma_f32_16x16x32_f16(al[m], bh[n], acc[m][n], 0, 0, 0);
                }
        }
        __syncthreads();
    }

    float* aRow = aB + (size_t)bb * L_ * L_;
    #pragma unroll
    for (int n = 0; n < 4; n++){
        int tcol = t0 + wn * 64 + n * 16 + l15;
        float w1v = w1b[tcol];
        #pragma unroll
        for (int m = 0; m < 4; m++){
            int sbase = s0 + wm * 64 + m * 16 + l4 * 4;
            #pragma unroll
            for (int r = 0; r < 4; r++){
                int s = sbase + r;
                aRow[(size_t)s * L_ + tcol] = acc[m][n][r] + w1v + w2b[s];
            }
        }
    }
}

// ---------------- row softmax: a-row (f32) -> p (fp16, in-place first half), m = rowmax ----------------
__global__ __launch_bounds__(256) void rowsm(float* __restrict__ aB, float* __restrict__ mws, int b0)
{
    __shared__ float red[4];
    int rowid = blockIdx.x;                          // bb*1024 + s
    int bb = rowid >> 10, s = rowid & 1023;
    float* row = aB + (size_t)rowid * L_;
    int tid = threadIdx.x;
    float4 v = ((const float4*)row)[tid];
    float mx = fmaxf(fmaxf(v.x, v.y), fmaxf(v.z, v.w));
    #pragma unroll
    for (int o = 32; o; o >>= 1) mx = fmaxf(mx, __shfl_xor(mx, o));
    if ((tid & 63) == 0) red[tid >> 6] = mx;
    __syncthreads();
    mx = fmaxf(fmaxf(red[0], red[1]), fmaxf(red[2], red[3]));
    float e0 = __expf(v.x - mx), e1 = __expf(v.y - mx), e2 = __expf(v.z - mx), e3 = __expf(v.w - mx);
    float sum = e0 + e1 + e2 + e3;
    #pragma unroll
    for (int o = 32; o; o >>= 1) sum += __shfl_xor(sum, o);
    __syncthreads();
    if ((tid & 63) == 0) red[tid >> 6] = sum;
    __syncthreads();
    sum = red[0] + red[1] + red[2] + red[3];
    float inv = 1.0f / sum;
    ushort4 pk;
    pk.x = f2h(e0 * inv); pk.y = f2h(e1 * inv); pk.z = f2h(e2 * inv); pk.w = f2h(e3 * inv);
    ((ushort4*)row)[tid] = pk;                       // p overwrites first 2KB of its own row
    if (tid == 0) mws[(size_t)(b0 + bb) * L_ + s] = mx;
}

// ---------------- p2 = softmax over s of m (per batch) ----------------
__global__ __launch_bounds__(1024) void p2k(const float* __restrict__ mws, float* __restrict__ p2, int b0)
{
    __shared__ float red[16];
    int bg = b0 + blockIdx.x;
    int tid = threadIdx.x;
    float v = mws[(size_t)bg * L_ + tid];
    float mx = v;
    #pragma unroll
    for (int o = 32; o; o >>= 1) mx = fmaxf(mx, __shfl_xor(mx, o));
    if ((tid & 63) == 0) red[tid >> 6] = mx;
    __syncthreads();
    float m2 = red[0];
    #pragma unroll
    for (int i = 1; i < 16; i++) m2 = fmaxf(m2, red[i]);
    float e = __expf(v - m2);
    float sum = e;
    #pragma unroll
    for (int o = 32; o; o >>= 1) sum += __shfl_xor(sum, o);
    __syncthreads();
    if ((tid & 63) == 0) red[tid >> 6] = sum;
    __syncthreads();
    float st = 0.f;
    #pragma unroll
    for (int i = 0; i < 16; i++) st += red[i];
    p2[(size_t)bg * L_ + tid] = e / st;
}

// ---------------- GEMM2: c = p @ q (fp16), fused output epilogue ----------------
__global__ __launch_bounds__(256) void gemm2(const float* __restrict__ aB, const u16* __restrict__ qT,
    const float* __restrict__ h, const float* __restrict__ p2, float* __restrict__ out, int b0)
{
    __shared__ u16 ldsA[128 * 64];
    __shared__ u16 ldsB[128 * 64];
    int bb = blockIdx.y;
    int bg = b0 + bb;
    int sm = blockIdx.x / 6;
    int dn = blockIdx.x % 6;
    int s0 = sm * 128, d0 = dn * 128;
    int tid = threadIdx.x;
    int lane = tid & 63, wid = tid >> 6;
    int wm = wid >> 1, wn = wid & 1;
    int l15 = lane & 15, l4 = lane >> 4;

    const char* Ab = (const char*)aB + ((size_t)bb * L_) * (L_ * 4);
    const u16* Bb = qT + (size_t)bb * D_ * L_;

    f32x4 acc[4][4];
    #pragma unroll
    for (int m = 0; m < 4; m++)
        #pragma unroll
        for (int n = 0; n < 4; n++)
            acc[m][n] = (f32x4){0.f, 0.f, 0.f, 0.f};

    for (int kb = 0; kb < L_; kb += 64){
        #pragma unroll
        for (int j = 0; j < 4; j++){                 // stage p tile (rows stride 4096B, fp16 payload)
            int n = j * 256 + tid;
            int row = n >> 3, c = n & 7;
            int cc = c ^ (row & 7);
            const u16* g = (const u16*)(Ab + ((size_t)(s0 + row) << 12)) + kb + cc * 8;
            gload_lds16(g, &ldsA[(j * 256 + wid * 64) * 8]);
        }
        #pragma unroll
        for (int j = 0; j < 4; j++){                 // stage qT tile
            int n = j * 256 + tid;
            int row = n >> 3, c = n & 7;
            int cc = c ^ (row & 7);
            const u16* g = Bb + (size_t)(d0 + row) * L_ + kb + cc * 8;
            gload_lds16(g, &ldsB[(j * 256 + wid * 64) * 8]);
        }
        __syncthreads();
        #pragma unroll
        for (int kk = 0; kk < 2; kk++){
            f16x8 af[4], bf[4];
            #pragma unroll
            for (int m = 0; m < 4; m++){
                int row = wm * 64 + m * 16 + l15;
                int c = kk * 4 + l4;
                af[m] = *(const f16x8*)&ldsA[(row * 8 + (c ^ (row & 7))) * 8];
            }
            #pragma unroll
            for (int n = 0; n < 4; n++){
                int row = wn * 64 + n * 16 + l15;
                int c = kk * 4 + l4;
                bf[n] = *(const f16x8*)&ldsB[(row * 8 + (c ^ (row & 7))) * 8];
            }
            #pragma unroll
            for (int m = 0; m < 4; m++)
                #pragma unroll
                for (int n = 0; n < 4; n++)
                    acc[m][n] = __builtin_amdgcn_mfma_f32_16x16x32_f16(af[m], bf[n], acc[m][n], 0, 0, 0);
        }
        __syncthreads();
    }

    #pragma unroll
    for (int m = 0; m < 4; m++){
        int sbase = s0 + wm * 64 + m * 16 + l4 * 4;
        #pragma unroll
        for (int r = 0; r < 4; r++){
            int s = sbase + r;
            float p2v = p2[(size_t)bg * L_ + s];
            size_t hb = ((size_t)bg * L_ + s) * D_;
            size_t ob = ((size_t)bg * L_ + s) * (4 * D_);
            #pragma unroll
            for (int n = 0; n < 4; n++){
                int d = d0 + wn * 64 + n * 16 + l15;
                float cv = acc[m][n][r];
                float hv = h[hb + d];
                float hc = hv * cv;
                out[ob + d]            = hv;
                out[ob + D_ + d]       = cv;
                out[ob + 2 * D_ + d]   = hc;
                out[ob + 3 * D_ + d]   = p2v * hc;
            }
        }
    }
}

extern "C" void kernel_launch(void* const* d_in, const int* in_sizes, int n_in,
                              void* d_out, int out_size, void* d_ws, size_t ws_size,
                              hipStream_t stream)
{
    const float* h   = (const float*)d_in[0];
    const float* q   = (const float*)d_in[1];
    const float* w1w = (const float*)d_in[2];
    const float* w1b = (const float*)d_in[3];
    const float* w2w = (const float*)d_in[4];
    const float* w2b = (const float*)d_in[5];
    float* out = (float*)d_out;

    const size_t szW2  = (size_t)L_ * D_ * 2;        // one fp16 plane of w2
    const size_t szM   = (size_t)B_ * L_ * 4;
    const size_t perB_hA = (size_t)L_ * D_ * 2;      // one fp16 plane of h
    const size_t perB_Bc = (size_t)L_ * K1_ * 2;     // one fp16 plane of Bcat
    const size_t perB_qT = (size_t)D_ * L_ * 2;
    const size_t perB_aB = (size_t)L_ * L_ * 4;
    const size_t perB = 2 * perB_hA + 2 * perB_Bc + perB_qT + perB_aB;   // 14.5 MiB
    const size_t fixed = 2 * szW2 + 2 * szM;

    int NB = 1;
    if (ws_size > fixed){
        size_t nbc = (ws_size - fixed) / perB;
        NB = (nbc >= 16) ? 16 : (nbc < 1 ? 1 : (int)nbc);
    }

    char* p = (char*)d_ws;
    u16*   w2h  = (u16*)p;   p += szW2;
    u16*   w2l  = (u16*)p;   p += szW2;
    float* mws  = (float*)p; p += szM;
    float* p2   = (float*)p; p += szM;
    u16*   hAh  = (u16*)p;   p += perB_hA * NB;
    u16*   hAl  = (u16*)p;   p += perB_hA * NB;
    u16*   Bch  = (u16*)p;   p += perB_Bc * NB;
    u16*   Bcl  = (u16*)p;   p += perB_Bc * NB;
    u16*   qT   = (u16*)p;   p += perB_qT * NB;
    float* aB   = (float*)p;

    for (int b0 = 0; b0 < B_; b0 += NB){
        int nb = (B_ - b0 < NB) ? (B_ - b0) : NB;
        prep_a<<<dim3(nb * 768), 256, 0, stream>>>(h, q, w1w, w2w, hAh, hAl, w2h, w2l, Bch, Bcl, b0, nb);
        prep_t<<<dim3(32, 24, nb), dim3(32, 8), 0, stream>>>(q, qT, b0);
        gemm1 <<<dim3(64, nb), 256, 0, stream>>>(hAh, hAl, w2h, w2l, Bch, Bcl, w1b, w2b, aB);
        rowsm <<<dim3(nb * 1024), 256, 0, stream>>>(aB, mws, b0);
        p2k   <<<dim3(nb), 1024, 0, stream>>>(mws, p2, b0);
        gemm2 <<<dim3(48, nb), 256, 0, stream>>>(aB, qT, h, p2, out, b0);
    }
}